// Round 3
// baseline (251.104 us; speedup 1.0000x reference)
//
#include <hip/hip_runtime.h>
#include <math.h>

// ---------------- workspace layout (float indices) ----------------
// Every location is WRITTEN before it is READ within one launch.
// No atomics, no memset, no read-modify-write on global memory.
#define WS_RED   0       // [1024] krecon per-block partial sums
#define WS_EN    1024    // [512]  kenergy per-block partial sums
#define WS_MU    2048    // [8][8]
#define WS_CINV  2112    // [8][64]
#define WS_COEF  2624    // [8]   phi_k / sqrt(det_cov_k)
#define WS_CD    2632    // [8]   per-k sum 1/diag(cov_k)
#define WS_STATP 4096    // [128][360] kstats per-block partials

static constexpr int NSAMP = 32 * 1024 * 8;       // B*T*C = 262144
static constexpr int NX4   = NSAMP * 64 / 4;      // 4194304 float4s in x
static constexpr int STAT_BLOCKS = 128;
static constexpr float EPSF = 1e-12f;

__device__ inline float wave_reduce_sum(float v) {
    #pragma unroll
    for (int m = 1; m < 64; m <<= 1) v += __shfl_xor(v, m, 64);
    return v;
}
__device__ inline double wave_reduce_sum_d(double v) {
    #pragma unroll
    for (int m = 1; m < 64; m <<= 1) v += __shfl_xor(v, m, 64);
    return v;
}

// ---------------- kernel A: reconstruction partials ----------------
__global__ __launch_bounds__(256) void krecon(const float4* __restrict__ x,
                                              const float4* __restrict__ xh,
                                              float* __restrict__ ws) {
    __shared__ float lds[4];
    float acc = 0.f;
    int stride = gridDim.x * blockDim.x;
    for (int i = blockIdx.x * blockDim.x + threadIdx.x; i < NX4; i += stride) {
        float4 a = x[i], b = xh[i];
        float d0 = b.x - a.x, d1 = b.y - a.y, d2 = b.z - a.z, d3 = b.w - a.w;
        acc = fmaf(d0, d0, acc);
        acc = fmaf(d1, d1, acc);
        acc = fmaf(d2, d2, acc);
        acc = fmaf(d3, d3, acc);
    }
    acc = wave_reduce_sum(acc);
    int w = threadIdx.x >> 6;
    if ((threadIdx.x & 63) == 0) lds[w] = acc;
    __syncthreads();
    if (threadIdx.x == 0)
        ws[WS_RED + blockIdx.x] = lds[0] + lds[1] + lds[2] + lds[3];
}

// ---------------- kernel B: GMM sufficient-stat partials ----------------
// 8 lanes per sample; lane's k = tid&7. Per-thread 45 accumulators:
// [0]=gsum, [1..9)=S1[d], [9..45)=S2 sym (j<=i). Block partial -> ws slot.
__global__ __launch_bounds__(256) void kstats(const float4* __restrict__ z4,
                                              const float* __restrict__ gamma,
                                              float* __restrict__ ws) {
    __shared__ float lds[4][360];
    float acc[45];
    #pragma unroll
    for (int i = 0; i < 45; ++i) acc[i] = 0.f;

    const int k    = threadIdx.x & 7;
    const int grp  = (blockIdx.x << 5) | (threadIdx.x >> 3);
    const int ngrp = gridDim.x << 5;            // 128*32 = 4096 groups

    for (int n = grp; n < NSAMP; n += ngrp) {   // 64 iterations
        float4 a = z4[n * 2], b = z4[n * 2 + 1];
        float zv[8] = {a.x, a.y, a.z, a.w, b.x, b.y, b.z, b.w};
        float g = gamma[n * 8 + k];
        acc[0] += g;
        float gz[8];
        #pragma unroll
        for (int i = 0; i < 8; ++i) { gz[i] = g * zv[i]; acc[1 + i] += gz[i]; }
        int t = 9;
        #pragma unroll
        for (int i = 0; i < 8; ++i) {
            #pragma unroll
            for (int j = 0; j <= i; ++j) { acc[t] = fmaf(gz[i], zv[j], acc[t]); ++t; }
        }
    }

    // reduce the 8 sample-groups within each wave (xor bits 3,4,5 keep k fixed)
    #pragma unroll
    for (int i = 0; i < 45; ++i) {
        float v = acc[i];
        v += __shfl_xor(v, 8, 64);
        v += __shfl_xor(v, 16, 64);
        v += __shfl_xor(v, 32, 64);
        acc[i] = v;
    }
    int lane = threadIdx.x & 63, w = threadIdx.x >> 6;
    if (lane < 8) {
        #pragma unroll
        for (int i = 0; i < 45; ++i) lds[w][lane * 45 + i] = acc[i];
    }
    __syncthreads();
    for (int v = threadIdx.x; v < 360; v += 256) {
        ws[WS_STATP + blockIdx.x * 360 + v] =
            lds[0][v] + lds[1][v] + lds[2][v] + lds[3][v];
    }
}

// ---------------- kernel C: reduce stats (f64) + per-component finalize ----
// Phase 1: 512 threads reduce 128 block-partials per slot into LDS (double).
// Phase 2: threads 0..7 do fp64 Cholesky / inverse / det for their k.
__global__ void kfinalize(float* __restrict__ ws) {
    __shared__ double sstat[360];
    for (int v = threadIdx.x; v < 360; v += 512) {
        double s = 0.0;
        for (int b = 0; b < STAT_BLOCKS; ++b)
            s += (double)ws[WS_STATP + b * 360 + v];
        sstat[v] = s;
    }
    __syncthreads();

    int k = threadIdx.x;
    if (k < 8) {
        const double* st = &sstat[k * 45];
        double g = st[0];
        double mu[8];
        for (int d = 0; d < 8; ++d) mu[d] = st[1 + d] / g;
        double A[8][8];
        {
            int t = 0;
            for (int i = 0; i < 8; ++i)
                for (int j = 0; j <= i; ++j) {
                    double v = st[9 + t] / g - mu[i] * mu[j];
                    A[i][j] = v; A[j][i] = v; ++t;
                }
        }
        for (int d = 0; d < 8; ++d) A[d][d] += (double)EPSF;

        double cd = 0.0;
        for (int d = 0; d < 8; ++d) cd += 1.0 / A[d][d];
        ws[WS_CD + k] = (float)cd;

        // Cholesky A = L L^T
        double L[8][8] = {};
        for (int i = 0; i < 8; ++i) {
            for (int j = 0; j <= i; ++j) {
                double s = A[i][j];
                for (int p = 0; p < j; ++p) s -= L[i][p] * L[j][p];
                if (i == j) L[i][i] = sqrt(s);
                else        L[i][j] = s / L[j][j];
            }
        }
        // M = L^{-1}
        double M[8][8] = {};
        for (int i = 0; i < 8; ++i) {
            M[i][i] = 1.0 / L[i][i];
            for (int j = 0; j < i; ++j) {
                double s = 0.0;
                for (int p = j; p < i; ++p) s -= L[i][p] * M[p][j];
                M[i][j] = s / L[i][i];
            }
        }
        // A^{-1} = M^T M
        for (int i = 0; i < 8; ++i)
            for (int j = 0; j < 8; ++j) {
                double s = 0.0;
                int p0 = i > j ? i : j;
                for (int p = p0; p < 8; ++p) s += M[p][i] * M[p][j];
                ws[WS_CINV + k * 64 + i * 8 + j] = (float)s;
            }

        // det_cov = prod(diag(chol(2pi*cov))) = (2pi)^4 * prod(diag(L));
        // reference divides by sqrt(det_cov)
        double det = 1.0;
        for (int d = 0; d < 8; ++d) det *= L[d][d];
        double c = 2.0 * M_PI;
        det *= c * c * c * c;
        double phi = g / (double)NSAMP;
        ws[WS_COEF + k] = (float)(phi / sqrt(det));
        for (int d = 0; d < 8; ++d) ws[WS_MU + k * 8 + d] = (float)mu[d];
    }
}

// ---------------- kernel D: sample-energy partials ----------------
__global__ __launch_bounds__(256) void kenergy(const float4* __restrict__ z4,
                                               float* __restrict__ ws) {
    __shared__ float smu[64], scinv[512], scoef[8], lds[4];
    for (int i = threadIdx.x; i < 64; i += 256) smu[i] = ws[WS_MU + i];
    for (int i = threadIdx.x; i < 512; i += 256) scinv[i] = ws[WS_CINV + i];
    if (threadIdx.x < 8) scoef[threadIdx.x] = ws[WS_COEF + threadIdx.x];
    __syncthreads();

    float acc = 0.f;
    int stride = gridDim.x * blockDim.x;          // 512*256 = 131072
    for (int n = blockIdx.x * blockDim.x + threadIdx.x; n < NSAMP; n += stride) {
        float4 a = z4[n * 2], b = z4[n * 2 + 1];
        float zv[8] = {a.x, a.y, a.z, a.w, b.x, b.y, b.z, b.w};
        float s = 0.f;
        #pragma unroll
        for (int k = 0; k < 8; ++k) {
            float dv[8];
            #pragma unroll
            for (int i = 0; i < 8; ++i) dv[i] = zv[i] - smu[k * 8 + i];
            float quad = 0.f;
            #pragma unroll
            for (int i = 0; i < 8; ++i) {
                float r = 0.f;
                #pragma unroll
                for (int j = 0; j < 8; ++j) r = fmaf(scinv[k * 64 + i * 8 + j], dv[j], r);
                quad = fmaf(dv[i], r, quad);
            }
            s = fmaf(scoef[k], __expf(-0.5f * quad), s);
        }
        acc += -__logf(s + EPSF);
    }
    acc = wave_reduce_sum(acc);
    int w = threadIdx.x >> 6;
    if ((threadIdx.x & 63) == 0) lds[w] = acc;
    __syncthreads();
    if (threadIdx.x == 0)
        ws[WS_EN + blockIdx.x] = lds[0] + lds[1] + lds[2] + lds[3];
}

// ---------------- kernel E: deterministic final combine (f64) ----------------
__global__ void kfinal(const float* __restrict__ ws, float* __restrict__ out) {
    __shared__ double ldsR[4], ldsE[4];
    double accR = 0.0, accE = 0.0;
    for (int i = threadIdx.x; i < 1024; i += 256) accR += (double)ws[WS_RED + i];
    for (int i = threadIdx.x; i < 512;  i += 256) accE += (double)ws[WS_EN + i];
    accR = wave_reduce_sum_d(accR);
    accE = wave_reduce_sum_d(accE);
    int w = threadIdx.x >> 6;
    if ((threadIdx.x & 63) == 0) { ldsR[w] = accR; ldsE[w] = accE; }
    __syncthreads();
    if (threadIdx.x == 0) {
        double R = ldsR[0] + ldsR[1] + ldsR[2] + ldsR[3];
        double E = ldsE[0] + ldsE[1] + ldsE[2] + ldsE[3];
        double cd = 0.0;
        for (int k = 0; k < 8; ++k) cd += (double)ws[WS_CD + k];
        double loss = R / ((double)NSAMP * 64.0)
                    + 0.1 * (E / (double)NSAMP)
                    + 0.005 * cd;
        out[0] = (float)loss;
    }
}

extern "C" void kernel_launch(void* const* d_in, const int* in_sizes, int n_in,
                              void* d_out, int out_size, void* d_ws, size_t ws_size,
                              hipStream_t stream) {
    const float* x     = (const float*)d_in[0];
    const float* xh    = (const float*)d_in[1];
    const float* z     = (const float*)d_in[2];
    const float* gamma = (const float*)d_in[3];
    float* ws = (float*)d_ws;

    krecon<<<1024, 256, 0, stream>>>((const float4*)x, (const float4*)xh, ws);
    kstats<<<STAT_BLOCKS, 256, 0, stream>>>((const float4*)z, gamma, ws);
    kfinalize<<<1, 512, 0, stream>>>(ws);
    kenergy<<<512, 256, 0, stream>>>((const float4*)z, ws);
    kfinal<<<1, 256, 0, stream>>>(ws, (float*)d_out);
}

// Round 4
// 202.968 us; speedup vs baseline: 1.2372x; 1.2372x over previous
//
#include <hip/hip_runtime.h>
#include <math.h>

// ---------------- workspace layout (float indices) ----------------
// Every location is WRITTEN before it is READ within one launch.
// No atomics, no memset, no read-modify-write on global memory.
#define WS_RED   0       // [2048] krecon per-block partials
#define WS_EN    2048    // [256]  kenergy per-block partials
#define WS_MU    2304    // [8][8]
#define WS_CINV  2368    // [8][64]
#define WS_COEF  2880    // [8]   phi_k / sqrt(det_cov_k)
#define WS_CD    2888    // [8]   per-k sum 1/diag(cov_k)
#define WS_STATP 4096    // [256][360] kstats per-block partials

static constexpr int NSAMP = 32 * 1024 * 8;       // B*T*C = 262144
static constexpr int NX4   = NSAMP * 64 / 4;      // 4194304 float4s in x
static constexpr int RE_BLOCKS   = 2048;
static constexpr int STAT_BLOCKS = 256;
static constexpr int EN_BLOCKS   = 256;
static constexpr float EPSF = 1e-12f;

__device__ inline float wave_reduce_sum(float v) {
    #pragma unroll
    for (int m = 1; m < 64; m <<= 1) v += __shfl_xor(v, m, 64);
    return v;
}
__device__ inline double wave_reduce_sum_d(double v) {
    #pragma unroll
    for (int m = 1; m < 64; m <<= 1) v += __shfl_xor(v, m, 64);
    return v;
}

// ---------------- kernel A: reconstruction partials ----------------
// 2048 blocks * 256 thr = 524288 threads; 8 float4-pairs each, exact cover.
__global__ __launch_bounds__(256) void krecon(const float4* __restrict__ x,
                                              const float4* __restrict__ xh,
                                              float* __restrict__ ws) {
    __shared__ float lds[4];
    float acc = 0.f;
    const int t = blockIdx.x * 256 + threadIdx.x;
    #pragma unroll 4
    for (int i = 0; i < 8; ++i) {
        int idx = t + i * (RE_BLOCKS * 256);
        float4 a = x[idx], b = xh[idx];
        float d0 = b.x - a.x, d1 = b.y - a.y, d2 = b.z - a.z, d3 = b.w - a.w;
        acc = fmaf(d0, d0, acc);
        acc = fmaf(d1, d1, acc);
        acc = fmaf(d2, d2, acc);
        acc = fmaf(d3, d3, acc);
    }
    acc = wave_reduce_sum(acc);
    int w = threadIdx.x >> 6;
    if ((threadIdx.x & 63) == 0) lds[w] = acc;
    __syncthreads();
    if (threadIdx.x == 0)
        ws[WS_RED + blockIdx.x] = lds[0] + lds[1] + lds[2] + lds[3];
}

// ---------------- kernel B: GMM sufficient-stat partials ----------------
// 8 lanes per sample; lane's k = tid&7. Per-thread 45 accumulators with
// STATIC indices only (9 + i*(i+1)/2 + j) — keeps acc[] in VGPRs.
__global__ __launch_bounds__(256) void kstats(const float4* __restrict__ z4,
                                              const float* __restrict__ gamma,
                                              float* __restrict__ ws) {
    __shared__ float lds[4][360];
    float acc[45];
    #pragma unroll
    for (int i = 0; i < 45; ++i) acc[i] = 0.f;

    const int k    = threadIdx.x & 7;
    const int grp  = (blockIdx.x << 5) | (threadIdx.x >> 3);
    constexpr int NGRP  = STAT_BLOCKS << 5;          // 8192 groups
    constexpr int ITERS = NSAMP / NGRP;              // 32

    for (int it = 0; it < ITERS; ++it) {
        int n = grp + it * NGRP;
        float4 a = z4[n * 2], b = z4[n * 2 + 1];
        float zv[8] = {a.x, a.y, a.z, a.w, b.x, b.y, b.z, b.w};
        float g = gamma[n * 8 + k];
        acc[0] += g;
        float gz[8];
        #pragma unroll
        for (int i = 0; i < 8; ++i) { gz[i] = g * zv[i]; acc[1 + i] += gz[i]; }
        #pragma unroll
        for (int i = 0; i < 8; ++i) {
            #pragma unroll
            for (int j = 0; j < 8; ++j) {
                if (j <= i)
                    acc[9 + (i * (i + 1)) / 2 + j] =
                        fmaf(gz[i], zv[j], acc[9 + (i * (i + 1)) / 2 + j]);
            }
        }
    }

    // reduce the 8 sample-groups within each wave (xor bits 3,4,5 keep k fixed)
    #pragma unroll
    for (int i = 0; i < 45; ++i) {
        float v = acc[i];
        v += __shfl_xor(v, 8, 64);
        v += __shfl_xor(v, 16, 64);
        v += __shfl_xor(v, 32, 64);
        acc[i] = v;
    }
    int lane = threadIdx.x & 63, w = threadIdx.x >> 6;
    if (lane < 8) {
        #pragma unroll
        for (int i = 0; i < 45; ++i) lds[w][lane * 45 + i] = acc[i];
    }
    __syncthreads();
    for (int v = threadIdx.x; v < 360; v += 256) {
        ws[WS_STATP + blockIdx.x * 360 + v] =
            lds[0][v] + lds[1][v] + lds[2][v] + lds[3][v];
    }
}

// ---------------- kernel C: reduce stats (f64) + per-component finalize ----
__global__ void kfinalize(float* __restrict__ ws) {
    __shared__ double sstat[360];
    for (int v = threadIdx.x; v < 360; v += 512) {
        double s = 0.0;
        for (int b = 0; b < STAT_BLOCKS; ++b)
            s += (double)ws[WS_STATP + b * 360 + v];
        sstat[v] = s;
    }
    __syncthreads();

    int k = threadIdx.x;
    if (k < 8) {
        const double* st = &sstat[k * 45];
        double g = st[0];
        double mu[8];
        for (int d = 0; d < 8; ++d) mu[d] = st[1 + d] / g;
        double A[8][8];
        {
            int t = 0;
            for (int i = 0; i < 8; ++i)
                for (int j = 0; j <= i; ++j) {
                    double v = st[9 + t] / g - mu[i] * mu[j];
                    A[i][j] = v; A[j][i] = v; ++t;
                }
        }
        for (int d = 0; d < 8; ++d) A[d][d] += (double)EPSF;

        double cd = 0.0;
        for (int d = 0; d < 8; ++d) cd += 1.0 / A[d][d];
        ws[WS_CD + k] = (float)cd;

        // Cholesky A = L L^T
        double L[8][8] = {};
        for (int i = 0; i < 8; ++i) {
            for (int j = 0; j <= i; ++j) {
                double s = A[i][j];
                for (int p = 0; p < j; ++p) s -= L[i][p] * L[j][p];
                if (i == j) L[i][i] = sqrt(s);
                else        L[i][j] = s / L[j][j];
            }
        }
        // M = L^{-1}
        double M[8][8] = {};
        for (int i = 0; i < 8; ++i) {
            M[i][i] = 1.0 / L[i][i];
            for (int j = 0; j < i; ++j) {
                double s = 0.0;
                for (int p = j; p < i; ++p) s -= L[i][p] * M[p][j];
                M[i][j] = s / L[i][i];
            }
        }
        // A^{-1} = M^T M
        for (int i = 0; i < 8; ++i)
            for (int j = 0; j < 8; ++j) {
                double s = 0.0;
                int p0 = i > j ? i : j;
                for (int p = p0; p < 8; ++p) s += M[p][i] * M[p][j];
                ws[WS_CINV + k * 64 + i * 8 + j] = (float)s;
            }

        // det_cov = prod(diag(chol(2pi*cov))) = (2pi)^4 * prod(diag(L));
        // reference divides by sqrt(det_cov)
        double det = 1.0;
        for (int d = 0; d < 8; ++d) det *= L[d][d];
        double c = 2.0 * M_PI;
        det *= c * c * c * c;
        double phi = g / (double)NSAMP;
        ws[WS_COEF + k] = (float)(phi / sqrt(det));
        for (int d = 0; d < 8; ++d) ws[WS_MU + k * 8 + d] = (float)mu[d];
    }
}

// ---------------- kernel D: sample-energy partials ----------------
// 256 blocks * 256 thr * 4 samples = exact cover. k-loop kept rolled
// (#pragma unroll 1) so the 512 cinv floats stay in LDS, not registers.
__global__ __launch_bounds__(256, 4) void kenergy(const float4* __restrict__ z4,
                                                  float* __restrict__ ws) {
    __shared__ float smu[64], scinv[512], scoef[8];
    __shared__ float lds[4];
    for (int i = threadIdx.x; i < 64; i += 256) smu[i] = ws[WS_MU + i];
    for (int i = threadIdx.x; i < 512; i += 256) scinv[i] = ws[WS_CINV + i];
    if (threadIdx.x < 8) scoef[threadIdx.x] = ws[WS_COEF + threadIdx.x];
    __syncthreads();

    const int base = blockIdx.x * 1024 + threadIdx.x;
    float zv[4][8];
    #pragma unroll
    for (int s = 0; s < 4; ++s) {
        int n = base + s * 256;
        float4 a = z4[n * 2], b = z4[n * 2 + 1];
        zv[s][0] = a.x; zv[s][1] = a.y; zv[s][2] = a.z; zv[s][3] = a.w;
        zv[s][4] = b.x; zv[s][5] = b.y; zv[s][6] = b.z; zv[s][7] = b.w;
    }
    float sacc[4] = {0.f, 0.f, 0.f, 0.f};

    #pragma unroll 1
    for (int k = 0; k < 8; ++k) {
        float muk[8];
        #pragma unroll
        for (int i = 0; i < 8; ++i) muk[i] = smu[k * 8 + i];
        float dv[4][8];
        float quad[4];
        #pragma unroll
        for (int s = 0; s < 4; ++s) {
            quad[s] = 0.f;
            #pragma unroll
            for (int i = 0; i < 8; ++i) dv[s][i] = zv[s][i] - muk[i];
        }
        #pragma unroll
        for (int i = 0; i < 8; ++i) {
            float4 c0 = *(const float4*)&scinv[k * 64 + i * 8];
            float4 c1 = *(const float4*)&scinv[k * 64 + i * 8 + 4];
            #pragma unroll
            for (int s = 0; s < 4; ++s) {
                float r;
                r = c0.x * dv[s][0];
                r = fmaf(c0.y, dv[s][1], r);
                r = fmaf(c0.z, dv[s][2], r);
                r = fmaf(c0.w, dv[s][3], r);
                r = fmaf(c1.x, dv[s][4], r);
                r = fmaf(c1.y, dv[s][5], r);
                r = fmaf(c1.z, dv[s][6], r);
                r = fmaf(c1.w, dv[s][7], r);
                quad[s] = fmaf(dv[s][i], r, quad[s]);
            }
        }
        float coef = scoef[k];
        #pragma unroll
        for (int s = 0; s < 4; ++s)
            sacc[s] = fmaf(coef, __expf(-0.5f * quad[s]), sacc[s]);
    }

    float acc = 0.f;
    #pragma unroll
    for (int s = 0; s < 4; ++s) acc += -__logf(sacc[s] + EPSF);

    acc = wave_reduce_sum(acc);
    int w = threadIdx.x >> 6;
    if ((threadIdx.x & 63) == 0) lds[w] = acc;
    __syncthreads();
    if (threadIdx.x == 0)
        ws[WS_EN + blockIdx.x] = lds[0] + lds[1] + lds[2] + lds[3];
}

// ---------------- kernel E: deterministic final combine (f64) ----------------
__global__ void kfinal(const float* __restrict__ ws, float* __restrict__ out) {
    __shared__ double ldsR[4], ldsE[4];
    double accR = 0.0, accE = 0.0;
    for (int i = threadIdx.x; i < RE_BLOCKS; i += 256) accR += (double)ws[WS_RED + i];
    for (int i = threadIdx.x; i < EN_BLOCKS; i += 256) accE += (double)ws[WS_EN + i];
    accR = wave_reduce_sum_d(accR);
    accE = wave_reduce_sum_d(accE);
    int w = threadIdx.x >> 6;
    if ((threadIdx.x & 63) == 0) { ldsR[w] = accR; ldsE[w] = accE; }
    __syncthreads();
    if (threadIdx.x == 0) {
        double R = ldsR[0] + ldsR[1] + ldsR[2] + ldsR[3];
        double E = ldsE[0] + ldsE[1] + ldsE[2] + ldsE[3];
        double cd = 0.0;
        for (int k = 0; k < 8; ++k) cd += (double)ws[WS_CD + k];
        double loss = R / ((double)NSAMP * 64.0)
                    + 0.1 * (E / (double)NSAMP)
                    + 0.005 * cd;
        out[0] = (float)loss;
    }
}

extern "C" void kernel_launch(void* const* d_in, const int* in_sizes, int n_in,
                              void* d_out, int out_size, void* d_ws, size_t ws_size,
                              hipStream_t stream) {
    const float* x     = (const float*)d_in[0];
    const float* xh    = (const float*)d_in[1];
    const float* z     = (const float*)d_in[2];
    const float* gamma = (const float*)d_in[3];
    float* ws = (float*)d_ws;

    krecon<<<RE_BLOCKS, 256, 0, stream>>>((const float4*)x, (const float4*)xh, ws);
    kstats<<<STAT_BLOCKS, 256, 0, stream>>>((const float4*)z, gamma, ws);
    kfinalize<<<1, 512, 0, stream>>>(ws);
    kenergy<<<EN_BLOCKS, 256, 0, stream>>>((const float4*)z, ws);
    kfinal<<<1, 256, 0, stream>>>(ws, (float*)d_out);
}

// Round 5
// 199.769 us; speedup vs baseline: 1.2570x; 1.0160x over previous
//
#include <hip/hip_runtime.h>
#include <math.h>

// ---------------- workspace layout (float indices) ----------------
// Every location is WRITTEN before it is READ within one launch.
// No atomics, no memset, no read-modify-write on global memory.
#define WS_RED   0       // [2048] krecon per-block partials
#define WS_EN    2048    // [1024] kenergy per-block partials
#define WS_MU    3072    // [8][8]
#define WS_CINV  3136    // [8][64]
#define WS_COEF  3648    // [8]   phi_k / sqrt(det_cov_k)
#define WS_CD    3656    // [8]   per-k sum 1/diag(cov_k)
#define WS_STATP 4096    // [256][360] kstats per-block partials

static constexpr int NSAMP = 32 * 1024 * 8;       // B*T*C = 262144
static constexpr int NX4   = NSAMP * 64 / 4;      // 4194304 float4s in x
static constexpr int RE_BLOCKS   = 2048;
static constexpr int STAT_BLOCKS = 256;
static constexpr int EN_BLOCKS   = 1024;
static constexpr float EPSF = 1e-12f;

__device__ inline float wave_reduce_sum(float v) {
    #pragma unroll
    for (int m = 1; m < 64; m <<= 1) v += __shfl_xor(v, m, 64);
    return v;
}
__device__ inline double wave_reduce_sum_d(double v) {
    #pragma unroll
    for (int m = 1; m < 64; m <<= 1) v += __shfl_xor(v, m, 64);
    return v;
}

// ---------------- kernel A: reconstruction partials ----------------
// 2048 blocks * 256 thr; each thread batch-loads 8+8 float4s (16 loads in
// flight) then reduces with 4 independent accumulators. Exact cover of NX4.
__global__ __launch_bounds__(256) void krecon(const float4* __restrict__ x,
                                              const float4* __restrict__ xh,
                                              float* __restrict__ ws) {
    __shared__ float lds[4];
    const int t = blockIdx.x * 256 + threadIdx.x;

    float4 xa[8], xb[8];
    #pragma unroll
    for (int i = 0; i < 8; ++i) xa[i] = x[t + i * (RE_BLOCKS * 256)];
    #pragma unroll
    for (int i = 0; i < 8; ++i) xb[i] = xh[t + i * (RE_BLOCKS * 256)];

    float a0 = 0.f, a1 = 0.f, a2 = 0.f, a3 = 0.f;
    #pragma unroll
    for (int i = 0; i < 8; ++i) {
        float d0 = xb[i].x - xa[i].x;
        float d1 = xb[i].y - xa[i].y;
        float d2 = xb[i].z - xa[i].z;
        float d3 = xb[i].w - xa[i].w;
        a0 = fmaf(d0, d0, a0);
        a1 = fmaf(d1, d1, a1);
        a2 = fmaf(d2, d2, a2);
        a3 = fmaf(d3, d3, a3);
    }
    float acc = (a0 + a1) + (a2 + a3);

    acc = wave_reduce_sum(acc);
    int w = threadIdx.x >> 6;
    if ((threadIdx.x & 63) == 0) lds[w] = acc;
    __syncthreads();
    if (threadIdx.x == 0)
        ws[WS_RED + blockIdx.x] = lds[0] + lds[1] + lds[2] + lds[3];
}

// ---------------- kernel B: GMM sufficient-stat partials ----------------
// 8 lanes per sample; lane's k = tid&7. Static-indexed acc[45] stays in
// VGPRs. Samples processed in batches of 4 so 12 loads are in flight.
__global__ __launch_bounds__(256) void kstats(const float4* __restrict__ z4,
                                              const float* __restrict__ gamma,
                                              float* __restrict__ ws) {
    __shared__ float lds[4][360];
    float acc[45];
    #pragma unroll
    for (int i = 0; i < 45; ++i) acc[i] = 0.f;

    const int k    = threadIdx.x & 7;
    const int grp  = (blockIdx.x << 5) | (threadIdx.x >> 3);
    constexpr int NGRP  = STAT_BLOCKS << 5;          // 8192 groups
    constexpr int ITERS = NSAMP / NGRP;              // 32

    for (int it = 0; it < ITERS; it += 4) {
        float4 za[4], zb[4];
        float gg[4];
        #pragma unroll
        for (int u = 0; u < 4; ++u) {
            int n = grp + (it + u) * NGRP;
            za[u] = z4[n * 2];
            zb[u] = z4[n * 2 + 1];
            gg[u] = gamma[n * 8 + k];
        }
        #pragma unroll
        for (int u = 0; u < 4; ++u) {
            float zv[8] = {za[u].x, za[u].y, za[u].z, za[u].w,
                           zb[u].x, zb[u].y, zb[u].z, zb[u].w};
            float g = gg[u];
            acc[0] += g;
            float gz[8];
            #pragma unroll
            for (int i = 0; i < 8; ++i) { gz[i] = g * zv[i]; acc[1 + i] += gz[i]; }
            #pragma unroll
            for (int i = 0; i < 8; ++i) {
                #pragma unroll
                for (int j = 0; j < 8; ++j) {
                    if (j <= i)
                        acc[9 + (i * (i + 1)) / 2 + j] =
                            fmaf(gz[i], zv[j], acc[9 + (i * (i + 1)) / 2 + j]);
                }
            }
        }
    }

    // reduce the 8 sample-groups within each wave (xor bits 3,4,5 keep k fixed)
    #pragma unroll
    for (int i = 0; i < 45; ++i) {
        float v = acc[i];
        v += __shfl_xor(v, 8, 64);
        v += __shfl_xor(v, 16, 64);
        v += __shfl_xor(v, 32, 64);
        acc[i] = v;
    }
    int lane = threadIdx.x & 63, w = threadIdx.x >> 6;
    if (lane < 8) {
        #pragma unroll
        for (int i = 0; i < 45; ++i) lds[w][lane * 45 + i] = acc[i];
    }
    __syncthreads();
    for (int v = threadIdx.x; v < 360; v += 256) {
        ws[WS_STATP + blockIdx.x * 360 + v] =
            lds[0][v] + lds[1][v] + lds[2][v] + lds[3][v];
    }
}

// ---------------- kernel C: reduce stats (f64) + per-component finalize ----
// Phase 1: thread v (<360) reduces its slot over 256 block-partials with 4
// independent f64 partials (ILP). Phase 2: threads 0..7 do fp64 Cholesky.
__global__ void kfinalize(float* __restrict__ ws) {
    __shared__ double sstat[360];
    int v = threadIdx.x;
    if (v < 360) {
        const float* p = &ws[WS_STATP + v];
        double s0 = 0.0, s1 = 0.0, s2 = 0.0, s3 = 0.0;
        #pragma unroll 4
        for (int b = 0; b < STAT_BLOCKS; b += 4) {
            s0 += (double)p[(b + 0) * 360];
            s1 += (double)p[(b + 1) * 360];
            s2 += (double)p[(b + 2) * 360];
            s3 += (double)p[(b + 3) * 360];
        }
        sstat[v] = (s0 + s1) + (s2 + s3);
    }
    __syncthreads();

    int k = threadIdx.x;
    if (k < 8) {
        const double* st = &sstat[k * 45];
        double g = st[0];
        double mu[8];
        for (int d = 0; d < 8; ++d) mu[d] = st[1 + d] / g;
        double A[8][8];
        {
            int t = 0;
            for (int i = 0; i < 8; ++i)
                for (int j = 0; j <= i; ++j) {
                    double val = st[9 + t] / g - mu[i] * mu[j];
                    A[i][j] = val; A[j][i] = val; ++t;
                }
        }
        for (int d = 0; d < 8; ++d) A[d][d] += (double)EPSF;

        double cd = 0.0;
        for (int d = 0; d < 8; ++d) cd += 1.0 / A[d][d];
        ws[WS_CD + k] = (float)cd;

        // Cholesky A = L L^T
        double L[8][8] = {};
        for (int i = 0; i < 8; ++i) {
            for (int j = 0; j <= i; ++j) {
                double s = A[i][j];
                for (int p = 0; p < j; ++p) s -= L[i][p] * L[j][p];
                if (i == j) L[i][i] = sqrt(s);
                else        L[i][j] = s / L[j][j];
            }
        }
        // M = L^{-1}
        double M[8][8] = {};
        for (int i = 0; i < 8; ++i) {
            M[i][i] = 1.0 / L[i][i];
            for (int j = 0; j < i; ++j) {
                double s = 0.0;
                for (int p = j; p < i; ++p) s -= L[i][p] * M[p][j];
                M[i][j] = s / L[i][i];
            }
        }
        // A^{-1} = M^T M
        for (int i = 0; i < 8; ++i)
            for (int j = 0; j < 8; ++j) {
                double s = 0.0;
                int p0 = i > j ? i : j;
                for (int p = p0; p < 8; ++p) s += M[p][i] * M[p][j];
                ws[WS_CINV + k * 64 + i * 8 + j] = (float)s;
            }

        // det_cov = prod(diag(chol(2pi*cov))) = (2pi)^4 * prod(diag(L));
        // reference divides by sqrt(det_cov)
        double det = 1.0;
        for (int d = 0; d < 8; ++d) det *= L[d][d];
        double c = 2.0 * M_PI;
        det *= c * c * c * c;
        double phi = g / (double)NSAMP;
        ws[WS_COEF + k] = (float)(phi / sqrt(det));
        for (int d = 0; d < 8; ++d) ws[WS_MU + k * 8 + d] = (float)mu[d];
    }
}

// ---------------- kernel D: sample-energy partials ----------------
// 1024 blocks * 256 thr * 1 sample = exact cover; 4 blocks/CU for latency
// hiding. k-loop rolled so the 512 cinv floats stay in LDS, not registers.
__global__ __launch_bounds__(256, 4) void kenergy(const float4* __restrict__ z4,
                                                  float* __restrict__ ws) {
    __shared__ float smu[64], scinv[512], scoef[8];
    __shared__ float lds[4];
    for (int i = threadIdx.x; i < 64; i += 256) smu[i] = ws[WS_MU + i];
    for (int i = threadIdx.x; i < 512; i += 256) scinv[i] = ws[WS_CINV + i];
    if (threadIdx.x < 8) scoef[threadIdx.x] = ws[WS_COEF + threadIdx.x];
    __syncthreads();

    const int n = blockIdx.x * 256 + threadIdx.x;
    float4 a = z4[n * 2], b = z4[n * 2 + 1];
    float zv[8] = {a.x, a.y, a.z, a.w, b.x, b.y, b.z, b.w};
    float sacc = 0.f;

    #pragma unroll 1
    for (int k = 0; k < 8; ++k) {
        float dv[8];
        #pragma unroll
        for (int i = 0; i < 8; ++i) dv[i] = zv[i] - smu[k * 8 + i];
        float quad = 0.f;
        #pragma unroll
        for (int i = 0; i < 8; ++i) {
            float4 c0 = *(const float4*)&scinv[k * 64 + i * 8];
            float4 c1 = *(const float4*)&scinv[k * 64 + i * 8 + 4];
            float r;
            r = c0.x * dv[0];
            r = fmaf(c0.y, dv[1], r);
            r = fmaf(c0.z, dv[2], r);
            r = fmaf(c0.w, dv[3], r);
            r = fmaf(c1.x, dv[4], r);
            r = fmaf(c1.y, dv[5], r);
            r = fmaf(c1.z, dv[6], r);
            r = fmaf(c1.w, dv[7], r);
            quad = fmaf(dv[i], r, quad);
        }
        sacc = fmaf(scoef[k], __expf(-0.5f * quad), sacc);
    }

    float acc = -__logf(sacc + EPSF);

    acc = wave_reduce_sum(acc);
    int w = threadIdx.x >> 6;
    if ((threadIdx.x & 63) == 0) lds[w] = acc;
    __syncthreads();
    if (threadIdx.x == 0)
        ws[WS_EN + blockIdx.x] = lds[0] + lds[1] + lds[2] + lds[3];
}

// ---------------- kernel E: deterministic final combine (f64) ----------------
__global__ void kfinal(const float* __restrict__ ws, float* __restrict__ out) {
    __shared__ double ldsR[4], ldsE[4];
    double accR = 0.0, accE = 0.0;
    #pragma unroll 4
    for (int i = threadIdx.x; i < RE_BLOCKS; i += 256) accR += (double)ws[WS_RED + i];
    #pragma unroll 4
    for (int i = threadIdx.x; i < EN_BLOCKS; i += 256) accE += (double)ws[WS_EN + i];
    accR = wave_reduce_sum_d(accR);
    accE = wave_reduce_sum_d(accE);
    int w = threadIdx.x >> 6;
    if ((threadIdx.x & 63) == 0) { ldsR[w] = accR; ldsE[w] = accE; }
    __syncthreads();
    if (threadIdx.x == 0) {
        double R = ldsR[0] + ldsR[1] + ldsR[2] + ldsR[3];
        double E = ldsE[0] + ldsE[1] + ldsE[2] + ldsE[3];
        double cd = 0.0;
        for (int k = 0; k < 8; ++k) cd += (double)ws[WS_CD + k];
        double loss = R / ((double)NSAMP * 64.0)
                    + 0.1 * (E / (double)NSAMP)
                    + 0.005 * cd;
        out[0] = (float)loss;
    }
}

extern "C" void kernel_launch(void* const* d_in, const int* in_sizes, int n_in,
                              void* d_out, int out_size, void* d_ws, size_t ws_size,
                              hipStream_t stream) {
    const float* x     = (const float*)d_in[0];
    const float* xh    = (const float*)d_in[1];
    const float* z     = (const float*)d_in[2];
    const float* gamma = (const float*)d_in[3];
    float* ws = (float*)d_ws;

    krecon<<<RE_BLOCKS, 256, 0, stream>>>((const float4*)x, (const float4*)xh, ws);
    kstats<<<STAT_BLOCKS, 256, 0, stream>>>((const float4*)z, gamma, ws);
    kfinalize<<<1, 512, 0, stream>>>(ws);
    kenergy<<<EN_BLOCKS, 256, 0, stream>>>((const float4*)z, ws);
    kfinal<<<1, 256, 0, stream>>>(ws, (float*)d_out);
}